// Round 1
// baseline (94.521 us; speedup 1.0000x reference)
//
#include <hip/hip_runtime.h>

// One thread = one event.
// x: [N, 20, 4, 3] = [N, 240] fp32 contiguous per event.
// Score: s[t] = bl[1] + sum_f x[e,t,f] * Wl[f,1]   (only column 1 used)
// MLP: 20 -> 80 -> 40 -> 21, relu on first two layers.
__global__ __launch_bounds__(256) void triplet_tagger_kernel(
    const float* __restrict__ x,    // [N,240]
    const float* __restrict__ Wl,   // [12,2]
    const float* __restrict__ bl,   // [2]
    const float* __restrict__ W1,   // [80,20]
    const float* __restrict__ b1,   // [80]
    const float* __restrict__ W2,   // [40,80]
    const float* __restrict__ b2,   // [40]
    const float* __restrict__ W3,   // [21,40]
    const float* __restrict__ b3,   // [21]
    float* __restrict__ out,        // [N,21]
    int n)
{
    const int ev = blockIdx.x * blockDim.x + threadIdx.x;
    if (ev >= n) return;

    // Wl column 1 (lane-uniform -> scalar loads)
    float wl[12];
#pragma unroll
    for (int f = 0; f < 12; ++f) wl[f] = Wl[f * 2 + 1];
    const float blv = bl[1];

    const float* __restrict__ xe = x + (size_t)ev * 240;

    // ---- score head: 20 triplets, dot-12 each ----
    float s[20];
#pragma unroll
    for (int t = 0; t < 20; ++t) {
        const float4* xt = reinterpret_cast<const float4*>(xe + t * 12);
        float4 a0 = xt[0];
        float4 a1 = xt[1];
        float4 a2 = xt[2];
        float acc = blv;
        acc += a0.x * wl[0] + a0.y * wl[1] + a0.z * wl[2]  + a0.w * wl[3];
        acc += a1.x * wl[4] + a1.y * wl[5] + a1.z * wl[6]  + a1.w * wl[7];
        acc += a2.x * wl[8] + a2.y * wl[9] + a2.z * wl[10] + a2.w * wl[11];
        s[t] = acc;
    }

    // ---- layer 1: 20 -> 80, relu ----
    float h1[80];
#pragma unroll
    for (int j = 0; j < 80; ++j) {
        const float* __restrict__ w = W1 + j * 20;
        float acc = b1[j];
#pragma unroll
        for (int k = 0; k < 20; ++k) acc += s[k] * w[k];
        h1[j] = fmaxf(acc, 0.0f);
    }

    // ---- layer 2: 80 -> 40, relu ----
    float h2[40];
#pragma unroll
    for (int j = 0; j < 40; ++j) {
        const float* __restrict__ w = W2 + j * 80;
        float acc = b2[j];
#pragma unroll
        for (int k = 0; k < 80; ++k) acc += h1[k] * w[k];
        h2[j] = fmaxf(acc, 0.0f);
    }

    // ---- layer 3: 40 -> 21 ----
    float* __restrict__ oe = out + (size_t)ev * 21;
#pragma unroll
    for (int j = 0; j < 21; ++j) {
        const float* __restrict__ w = W3 + j * 40;
        float acc = b3[j];
#pragma unroll
        for (int k = 0; k < 40; ++k) acc += h2[k] * w[k];
        oe[j] = acc;
    }
}

extern "C" void kernel_launch(void* const* d_in, const int* in_sizes, int n_in,
                              void* d_out, int out_size, void* d_ws, size_t ws_size,
                              hipStream_t stream) {
    const float* x  = (const float*)d_in[0];
    const float* Wl = (const float*)d_in[1];
    const float* bl = (const float*)d_in[2];
    const float* W1 = (const float*)d_in[3];
    const float* b1 = (const float*)d_in[4];
    const float* W2 = (const float*)d_in[5];
    const float* b2 = (const float*)d_in[6];
    const float* W3 = (const float*)d_in[7];
    const float* b3 = (const float*)d_in[8];
    float* out = (float*)d_out;

    const int n = in_sizes[0] / 240;  // number of events
    const int block = 256;
    const int grid = (n + block - 1) / block;
    triplet_tagger_kernel<<<grid, block, 0, stream>>>(
        x, Wl, bl, W1, b1, W2, b2, W3, b3, out, n);
}